// Round 1
// baseline (5178.786 us; speedup 1.0000x reference)
//
#include <hip/hip_runtime.h>
#include <math.h>

// Problem dims
#define Bn 4
#define Tn 1024
#define Fn 128
#define Hn 16
#define SCALING 0.08838834764831845f   // 128^-0.5

// Workspace layout (float offsets)
#define Q_OFF    0            // 64*1024*128
#define K_OFF    8388608
#define V_OFF    16777216
#define ATTN_OFF 25165824     // [4][32][1024][128]
#define M_OFF    41943040     // [64][1024]
#define L_OFF    42008576
#define AWF_OFF  42074112     // [64][128][128]

// ---------------------------------------------------------------------------
// K1: conv1  x[4][128][1024][128] * w[48][128][3][3] -> relu(q*scale), relu(k), relu(v)
// block: 16 ocs x (8 t-rows x 128 f). grid = 4 * 128 * 3
__global__ __launch_bounds__(256) void conv_in_kernel(
    const float* __restrict__ x, const float* __restrict__ w, const float* __restrict__ bias,
    float* __restrict__ qb, float* __restrict__ kb, float* __restrict__ vb)
{
    __shared__ float ws[18432];     // 16 oc x 128 ic x 9
    __shared__ float it[10][130];
    const int tid = threadIdx.x;
    const int bz  = blockIdx.x;
    const int ocg = bz % 3;
    const int tt  = (bz / 3) & 127;
    const int b   = bz / 384;
    const int t0  = tt * 8;

    const float* wbase = w + ocg * 18432;
    for (int i = tid; i < 18432; i += 256) ws[i] = wbase[i];

    float acc[16][4];
#pragma unroll
    for (int j = 0; j < 16; ++j)
#pragma unroll
        for (int k2 = 0; k2 < 4; ++k2) acc[j][k2] = 0.f;

    const int r0  = tid >> 7;     // 0..1
    const int col = tid & 127;

    for (int ic = 0; ic < 128; ++ic) {
        __syncthreads();
        const float* xc = x + ((size_t)(b * 128 + ic) * 1024) * 128;
        for (int i = tid; i < 1300; i += 256) {
            int rr = i / 130, cc = i - rr * 130;
            int t = t0 - 1 + rr, f = cc - 1;
            float v = 0.f;
            if ((unsigned)t < 1024u && (unsigned)f < 128u) v = xc[t * 128 + f];
            it[rr][cc] = v;
        }
        __syncthreads();
        float in[9][3];
#pragma unroll
        for (int i = 0; i < 9; ++i)
#pragma unroll
            for (int j = 0; j < 3; ++j)
                in[i][j] = it[r0 + i][col + j];
        const float* wp = ws + ic * 9;
#pragma unroll
        for (int j = 0; j < 16; ++j) {
            const float* wj = wp + j * 1152;
            float w0 = wj[0], w1 = wj[1], w2 = wj[2], w3 = wj[3], w4 = wj[4],
                  w5 = wj[5], w6 = wj[6], w7 = wj[7], w8 = wj[8];
#pragma unroll
            for (int k2 = 0; k2 < 4; ++k2) {
                int rb = 2 * k2;
                acc[j][k2] += w0 * in[rb][0]     + w1 * in[rb][1]     + w2 * in[rb][2]
                            + w3 * in[rb + 1][0] + w4 * in[rb + 1][1] + w5 * in[rb + 1][2]
                            + w6 * in[rb + 2][0] + w7 * in[rb + 2][1] + w8 * in[rb + 2][2];
            }
        }
    }

    float* dst = (ocg == 0) ? qb : (ocg == 1) ? kb : vb;
    const float scale = (ocg == 0) ? SCALING : 1.0f;
#pragma unroll
    for (int j = 0; j < 16; ++j) {
        float bv = bias[ocg * 16 + j];
#pragma unroll
        for (int k2 = 0; k2 < 4; ++k2) {
            float v = (acc[j][k2] + bv) * scale;
            v = fmaxf(v, 0.f);
            int t = t0 + r0 + 2 * k2;
            dst[((size_t)(b * 16 + j) * 1024 + t) * 128 + col] = v;
        }
    }
}

// ---------------------------------------------------------------------------
// K2: flash time attention per (bh, 64-row t block); writes attn_t + per-row m,l
__global__ __launch_bounds__(256) void attn_time_kernel(
    const float* __restrict__ qb, const float* __restrict__ kb, const float* __restrict__ vb,
    float* __restrict__ attn, float* __restrict__ mout, float* __restrict__ lout)
{
    __shared__ float Qs[64][132];
    __shared__ float Ks[32][132];
    __shared__ float Vs[32][128];
    __shared__ float Ss[64][33];
    __shared__ float mrow[64], lrow[64], crow[64];

    const int tid = threadIdx.x;
    const int bh = blockIdx.x >> 4;
    const int t0 = (blockIdx.x & 15) << 6;

    const float4* qp4 = (const float4*)(qb + ((size_t)bh * 1024 + t0) * 128);
    for (int i = tid; i < 2048; i += 256) {
        int r = i >> 5, c = i & 31;
        *((float4*)&Qs[r][0] + c) = qp4[i];
    }
    if (tid < 64) { mrow[tid] = -INFINITY; lrow[tid] = 0.f; }

    float o0[16], o1[16];
#pragma unroll
    for (int j = 0; j < 16; ++j) { o0[j] = 0.f; o1[j] = 0.f; }

    const int tq = tid >> 4, sc = tid & 15;
    const int rg = tid & 31, cg = tid >> 5;

    const float4* kp4 = (const float4*)(kb + (size_t)bh * 1024 * 128);
    const float4* vp4 = (const float4*)(vb + (size_t)bh * 1024 * 128);

    for (int sb = 0; sb < 32; ++sb) {
        __syncthreads();
        for (int i = tid; i < 1024; i += 256) {
            int r = i >> 5, c = i & 31;
            *((float4*)&Ks[r][0] + c) = kp4[sb * 1024 + i];
            *((float4*)&Vs[r][0] + c) = vp4[sb * 1024 + i];
        }
        __syncthreads();

        float s[4][2] = {};
#pragma unroll
        for (int kk = 0; kk < 32; ++kk) {
            float4 k0 = *(const float4*)&Ks[sc][kk * 4];
            float4 k1 = *(const float4*)&Ks[sc + 16][kk * 4];
#pragma unroll
            for (int i = 0; i < 4; ++i) {
                float4 q4 = *(const float4*)&Qs[tq * 4 + i][kk * 4];
                s[i][0] += q4.x * k0.x; s[i][0] += q4.y * k0.y;
                s[i][0] += q4.z * k0.z; s[i][0] += q4.w * k0.w;
                s[i][1] += q4.x * k1.x; s[i][1] += q4.y * k1.y;
                s[i][1] += q4.z * k1.z; s[i][1] += q4.w * k1.w;
            }
        }
#pragma unroll
        for (int i = 0; i < 4; ++i) {
            Ss[tq * 4 + i][sc]      = s[i][0];
            Ss[tq * 4 + i][sc + 16] = s[i][1];
        }
        __syncthreads();

        {
            const int r = tid >> 2, p = tid & 3;
            float mloc = -INFINITY;
#pragma unroll
            for (int j = 0; j < 8; ++j) mloc = fmaxf(mloc, Ss[r][p * 8 + j]);
            mloc = fmaxf(mloc, __shfl_xor(mloc, 1));
            mloc = fmaxf(mloc, __shfl_xor(mloc, 2));
            float mold = mrow[r];
            float mnew = fmaxf(mold, mloc);
            float ssum = 0.f;
#pragma unroll
            for (int j = 0; j < 8; ++j) {
                float e = __expf(Ss[r][p * 8 + j] - mnew);
                Ss[r][p * 8 + j] = e;
                ssum += e;
            }
            ssum += __shfl_xor(ssum, 1);
            ssum += __shfl_xor(ssum, 2);
            if (p == 0) {
                float c = __expf(mold - mnew);
                crow[r] = c;
                mrow[r] = mnew;
                lrow[r] = lrow[r] * c + ssum;
            }
        }
        __syncthreads();

        const float c0 = crow[rg * 2], c1 = crow[rg * 2 + 1];
#pragma unroll
        for (int j = 0; j < 16; ++j) { o0[j] *= c0; o1[j] *= c1; }
#pragma unroll
        for (int s2 = 0; s2 < 32; ++s2) {
            float p0 = Ss[rg * 2][s2], p1 = Ss[rg * 2 + 1][s2];
#pragma unroll
            for (int j4 = 0; j4 < 4; ++j4) {
                float4 v4 = *(const float4*)&Vs[s2][cg * 16 + j4 * 4];
                o0[j4 * 4 + 0] += p0 * v4.x; o0[j4 * 4 + 1] += p0 * v4.y;
                o0[j4 * 4 + 2] += p0 * v4.z; o0[j4 * 4 + 3] += p0 * v4.w;
                o1[j4 * 4 + 0] += p1 * v4.x; o1[j4 * 4 + 1] += p1 * v4.y;
                o1[j4 * 4 + 2] += p1 * v4.z; o1[j4 * 4 + 3] += p1 * v4.w;
            }
        }
    }
    __syncthreads();
    const float rl0 = 1.f / lrow[rg * 2], rl1 = 1.f / lrow[rg * 2 + 1];
    const int b = bh >> 4, h = bh & 15;
    float* op = attn + (((size_t)(b * 32 + h)) * 1024 + t0) * 128;
#pragma unroll
    for (int j4 = 0; j4 < 4; ++j4) {
        float4 u0, u1;
        u0.x = o0[j4 * 4 + 0] * rl0; u0.y = o0[j4 * 4 + 1] * rl0;
        u0.z = o0[j4 * 4 + 2] * rl0; u0.w = o0[j4 * 4 + 3] * rl0;
        u1.x = o1[j4 * 4 + 0] * rl1; u1.y = o1[j4 * 4 + 1] * rl1;
        u1.z = o1[j4 * 4 + 2] * rl1; u1.w = o1[j4 * 4 + 3] * rl1;
        *(float4*)&op[(size_t)(rg * 2) * 128 + cg * 16 + j4 * 4] = u0;
        *(float4*)&op[(size_t)(rg * 2 + 1) * 128 + cg * 16 + j4 * 4] = u1;
    }
    if (tid < 64) {
        mout[(size_t)bh * 1024 + t0 + tid] = mrow[tid];
        lout[(size_t)bh * 1024 + t0 + tid] = lrow[tid];
    }
}

// ---------------------------------------------------------------------------
// K3: aw_avg[b][t][s] = (1/16) sum_h exp(S - m)/l  (recompute scores)
__global__ __launch_bounds__(256) void aw_avg_kernel(
    const float* __restrict__ qb, const float* __restrict__ kb,
    const float* __restrict__ mbuf, const float* __restrict__ lbuf,
    float* __restrict__ aw)
{
    __shared__ float Qs[64][132];
    __shared__ float Ks[64][132];
    const int tid = threadIdx.x;
    const int bz = blockIdx.x;
    const int sbk = bz & 15, tbk = (bz >> 4) & 15, b = bz >> 8;
    const int t0 = tbk << 6, s0 = sbk << 6;
    const int tq = tid >> 4, sc = tid & 15;
    float acc[4][4] = {};
    for (int h = 0; h < 16; ++h) {
        const int bh = b * 16 + h;
        __syncthreads();
        const float4* qp4 = (const float4*)(qb + ((size_t)bh * 1024 + t0) * 128);
        const float4* kp4 = (const float4*)(kb + ((size_t)bh * 1024 + s0) * 128);
        for (int i = tid; i < 2048; i += 256) {
            int r = i >> 5, c = i & 31;
            *((float4*)&Qs[r][0] + c) = qp4[i];
            *((float4*)&Ks[r][0] + c) = kp4[i];
        }
        __syncthreads();
        float s[4][4] = {};
#pragma unroll
        for (int kk = 0; kk < 32; ++kk) {
            float4 k4[4], q4[4];
#pragma unroll
            for (int j = 0; j < 4; ++j) k4[j] = *(const float4*)&Ks[sc + 16 * j][kk * 4];
#pragma unroll
            for (int i = 0; i < 4; ++i) q4[i] = *(const float4*)&Qs[tq * 4 + i][kk * 4];
#pragma unroll
            for (int i = 0; i < 4; ++i)
#pragma unroll
                for (int j = 0; j < 4; ++j)
                    s[i][j] += q4[i].x * k4[j].x + q4[i].y * k4[j].y
                             + q4[i].z * k4[j].z + q4[i].w * k4[j].w;
        }
#pragma unroll
        for (int i = 0; i < 4; ++i) {
            float mh = mbuf[(size_t)bh * 1024 + t0 + tq * 4 + i];
            float rl = 1.f / lbuf[(size_t)bh * 1024 + t0 + tq * 4 + i];
#pragma unroll
            for (int j = 0; j < 4; ++j)
                acc[i][j] += __expf(s[i][j] - mh) * rl;
        }
    }
    const float inv = 1.f / 16.f;
#pragma unroll
    for (int i = 0; i < 4; ++i)
#pragma unroll
        for (int j = 0; j < 4; ++j)
            aw[((size_t)b * 1024 + t0 + tq * 4 + i) * 1024 + s0 + sc + 16 * j] = acc[i][j] * inv;
}

// ---------------------------------------------------------------------------
// K4a: freq scores G = softmax_g(q^T k over t), one block per bh
__global__ __launch_bounds__(256) void freq_aw_kernel(
    const float* __restrict__ qb, const float* __restrict__ kb, float* __restrict__ awf)
{
    __shared__ float Qc[32][132];
    __shared__ float Kc[32][132];
    const int tid = threadIdx.x;
    const int bh = blockIdx.x;
    const int fg = tid >> 4, gg = tid & 15;
    float s[8][8] = {};
    const float4* qp4 = (const float4*)(qb + (size_t)bh * 1024 * 128);
    const float4* kp4 = (const float4*)(kb + (size_t)bh * 1024 * 128);
    for (int tc = 0; tc < 32; ++tc) {
        __syncthreads();
        for (int i = tid; i < 1024; i += 256) {
            int r = i >> 5, c = i & 31;
            *((float4*)&Qc[r][0] + c) = qp4[tc * 1024 + i];
            *((float4*)&Kc[r][0] + c) = kp4[tc * 1024 + i];
        }
        __syncthreads();
#pragma unroll 4
        for (int t = 0; t < 32; ++t) {
            float qv[8], kv[8];
#pragma unroll
            for (int i = 0; i < 8; ++i) qv[i] = Qc[t][fg + 16 * i];
#pragma unroll
            for (int j = 0; j < 8; ++j) kv[j] = Kc[t][gg + 16 * j];
#pragma unroll
            for (int i = 0; i < 8; ++i)
#pragma unroll
                for (int j = 0; j < 8; ++j)
                    s[i][j] += qv[i] * kv[j];
        }
    }
#pragma unroll
    for (int i = 0; i < 8; ++i) {
        float mx = -INFINITY;
#pragma unroll
        for (int j = 0; j < 8; ++j) mx = fmaxf(mx, s[i][j]);
        mx = fmaxf(mx, __shfl_xor(mx, 1));
        mx = fmaxf(mx, __shfl_xor(mx, 2));
        mx = fmaxf(mx, __shfl_xor(mx, 4));
        mx = fmaxf(mx, __shfl_xor(mx, 8));
        float sum = 0.f;
        float e[8];
#pragma unroll
        for (int j = 0; j < 8; ++j) { e[j] = __expf(s[i][j] - mx); sum += e[j]; }
        sum += __shfl_xor(sum, 1); sum += __shfl_xor(sum, 2);
        sum += __shfl_xor(sum, 4); sum += __shfl_xor(sum, 8);
        float r = 1.f / sum;
#pragma unroll
        for (int j = 0; j < 8; ++j)
            awf[((size_t)bh * 128 + fg + 16 * i) * 128 + gg + 16 * j] = e[j] * r;
    }
}

// ---------------------------------------------------------------------------
// K4b: attn_f[b][16+h][t][f] = sum_g G'[f][g] * v[t][g]; per (bh, 32-row t chunk)
__global__ __launch_bounds__(256) void freq_attn_kernel(
    const float* __restrict__ awf, const float* __restrict__ vb, float* __restrict__ attn)
{
    __shared__ float GT[128][132];   // transposed weights: GT[g][f]
    __shared__ float Vc[32][133];
    const int tid = threadIdx.x;
    const int bh = blockIdx.x >> 5;
    const int t0 = (blockIdx.x & 31) << 5;
    const int b = bh >> 4, h = bh & 15;

    const float* gp = awf + (size_t)bh * 128 * 128;
    for (int i = tid; i < 16384; i += 256) {
        int f = i >> 7, g = i & 127;
        GT[g][f] = gp[i];
    }
    const float* vp = vb + ((size_t)bh * 1024 + t0) * 128;
    for (int i = tid; i < 4096; i += 256) {
        int r = i >> 7, c = i & 127;
        Vc[r][c] = vp[i];
    }
    __syncthreads();

    const int tg = tid >> 3;    // 0..31 -> t row
    const int fq = tid & 7;     // f block of 16
    float acc[16] = {};
    for (int g = 0; g < 128; ++g) {
        float vv = Vc[tg][g];
#pragma unroll
        for (int j4 = 0; j4 < 4; ++j4) {
            float4 g4 = *(const float4*)&GT[g][fq * 16 + j4 * 4];
            acc[j4 * 4 + 0] += g4.x * vv; acc[j4 * 4 + 1] += g4.y * vv;
            acc[j4 * 4 + 2] += g4.z * vv; acc[j4 * 4 + 3] += g4.w * vv;
        }
    }
    float* op = attn + (((size_t)(b * 32 + 16 + h)) * 1024 + t0 + tg) * 128 + fq * 16;
#pragma unroll
    for (int j4 = 0; j4 < 4; ++j4) {
        float4 u;
        u.x = acc[j4 * 4 + 0]; u.y = acc[j4 * 4 + 1];
        u.z = acc[j4 * 4 + 2]; u.w = acc[j4 * 4 + 3];
        *(float4*)&op[j4 * 4] = u;
    }
}

// ---------------------------------------------------------------------------
// K5: conv2  attn[4][32][1024][128] * w[128][32][3][3] -> relu -> out
__global__ __launch_bounds__(256) void conv_out_kernel(
    const float* __restrict__ x, const float* __restrict__ w, const float* __restrict__ bias,
    float* __restrict__ out)
{
    __shared__ float ws[4608];      // 16 oc x 32 ic x 9
    __shared__ float it[10][130];
    const int tid = threadIdx.x;
    const int bz  = blockIdx.x;
    const int ocg = bz & 7;
    const int tt  = (bz >> 3) & 127;
    const int b   = bz >> 10;
    const int t0  = tt * 8;

    const float* wbase = w + ocg * 4608;
    for (int i = tid; i < 4608; i += 256) ws[i] = wbase[i];

    float acc[16][4];
#pragma unroll
    for (int j = 0; j < 16; ++j)
#pragma unroll
        for (int k2 = 0; k2 < 4; ++k2) acc[j][k2] = 0.f;

    const int r0  = tid >> 7;
    const int col = tid & 127;

    for (int ic = 0; ic < 32; ++ic) {
        __syncthreads();
        const float* xc = x + ((size_t)(b * 32 + ic) * 1024) * 128;
        for (int i = tid; i < 1300; i += 256) {
            int rr = i / 130, cc = i - rr * 130;
            int t = t0 - 1 + rr, f = cc - 1;
            float v = 0.f;
            if ((unsigned)t < 1024u && (unsigned)f < 128u) v = xc[t * 128 + f];
            it[rr][cc] = v;
        }
        __syncthreads();
        float in[9][3];
#pragma unroll
        for (int i = 0; i < 9; ++i)
#pragma unroll
            for (int j = 0; j < 3; ++j)
                in[i][j] = it[r0 + i][col + j];
        const float* wp = ws + ic * 9;
#pragma unroll
        for (int j = 0; j < 16; ++j) {
            const float* wj = wp + j * 288;
            float w0 = wj[0], w1 = wj[1], w2 = wj[2], w3 = wj[3], w4 = wj[4],
                  w5 = wj[5], w6 = wj[6], w7 = wj[7], w8 = wj[8];
#pragma unroll
            for (int k2 = 0; k2 < 4; ++k2) {
                int rb = 2 * k2;
                acc[j][k2] += w0 * in[rb][0]     + w1 * in[rb][1]     + w2 * in[rb][2]
                            + w3 * in[rb + 1][0] + w4 * in[rb + 1][1] + w5 * in[rb + 1][2]
                            + w6 * in[rb + 2][0] + w7 * in[rb + 2][1] + w8 * in[rb + 2][2];
            }
        }
    }

#pragma unroll
    for (int j = 0; j < 16; ++j) {
        int oc = ocg * 16 + j;
        float bv = bias[oc];
#pragma unroll
        for (int k2 = 0; k2 < 4; ++k2) {
            float v = fmaxf(acc[j][k2] + bv, 0.f);
            int t = t0 + r0 + 2 * k2;
            out[((size_t)(b * 128 + oc) * 1024 + t) * 128 + col] = v;
        }
    }
}

// ---------------------------------------------------------------------------
extern "C" void kernel_launch(void* const* d_in, const int* in_sizes, int n_in,
                              void* d_out, int out_size, void* d_ws, size_t ws_size,
                              hipStream_t stream) {
    const float* query = (const float*)d_in[0];
    const float* in_w  = (const float*)d_in[1];
    const float* in_b  = (const float*)d_in[2];
    const float* out_w = (const float*)d_in[3];
    const float* out_b = (const float*)d_in[4];
    float* out = (float*)d_out;
    float* aw  = out + (size_t)67108864;      // [4][1024][1024]
    float* wsf = (float*)d_ws;
    float* qb    = wsf + Q_OFF;
    float* kb    = wsf + K_OFF;
    float* vb    = wsf + V_OFF;
    float* attnb = wsf + ATTN_OFF;
    float* mb    = wsf + M_OFF;
    float* lb    = wsf + L_OFF;
    float* awfb  = wsf + AWF_OFF;

    hipLaunchKernelGGL(conv_in_kernel,  dim3(1536), dim3(256), 0, stream, query, in_w, in_b, qb, kb, vb);
    hipLaunchKernelGGL(attn_time_kernel, dim3(1024), dim3(256), 0, stream, qb, kb, vb, attnb, mb, lb);
    hipLaunchKernelGGL(aw_avg_kernel,   dim3(1024), dim3(256), 0, stream, qb, kb, mb, lb, aw);
    hipLaunchKernelGGL(freq_aw_kernel,  dim3(64),   dim3(256), 0, stream, qb, kb, awfb);
    hipLaunchKernelGGL(freq_attn_kernel, dim3(2048), dim3(256), 0, stream, awfb, vb, attnb);
    hipLaunchKernelGGL(conv_out_kernel, dim3(4096), dim3(256), 0, stream, attnb, out_w, out_b, out);
}